// Round 1
// baseline (179.000 us; speedup 1.0000x reference)
//
#include <hip/hip_runtime.h>
#include <cstdint>

// Problem constants
#define B_   8
#define C_   256
#define H_   64
#define W_   64
#define HW_  4096
#define NH_  8
#define NP_  4
#define DH_  32
#define G_   64   // B*NH

// ---------------------------------------------------------------------------
// Kernel 1: ow = q @ w_off^T + b_off, softmax over points, emit (x,y,wt) per
// (b,hw,head,point) as float4. One block = 64 hw rows of one batch.
// ---------------------------------------------------------------------------
__global__ __launch_bounds__(256) void k_offsets(const float* __restrict__ query,
                                                 const float* __restrict__ w_off,
                                                 const float* __restrict__ b_off,
                                                 float4* __restrict__ params) {
  __shared__ float lds[64 * 257];  // q tile [hw][c] padded; reused as ow tile [64][97]
  const int bid = blockIdx.x;
  const int b   = bid >> 6;
  const int hw0 = (bid & 63) << 6;
  const int t   = threadIdx.x;

  const float* qb = query + (size_t)b * C_ * HW_ + hw0;
  // stage 64 hw x 256 c (coalesced over hw)
  #pragma unroll
  for (int k = 0; k < 64; ++k) {
    int idx = t + k * 256;
    int c = idx >> 6, hwl = idx & 63;
    lds[hwl * 257 + c] = qb[c * HW_ + hwl];
  }
  __syncthreads();

  const int sub = t >> 5, ol = t & 31;  // 8 row-subgroups x 32 output lanes
  float acc0[8], acc1[8], acc2[8];
  #pragma unroll
  for (int j = 0; j < 8; ++j) { acc0[j] = 0.f; acc1[j] = 0.f; acc2[j] = 0.f; }

  const float* wp0 = w_off + ol * 256;
  const float* wp1 = wp0 + 32 * 256;
  const float* wp2 = wp0 + 64 * 256;
  const float* ql  = lds + (sub * 8) * 257;

  #pragma unroll 4
  for (int c = 0; c < 256; ++c) {
    float w0 = wp0[c], w1 = wp1[c], w2 = wp2[c];
    #pragma unroll
    for (int j = 0; j < 8; ++j) {
      float qv = ql[j * 257 + c];
      acc0[j] = fmaf(qv, w0, acc0[j]);
      acc1[j] = fmaf(qv, w1, acc1[j]);
      acc2[j] = fmaf(qv, w2, acc2[j]);
    }
  }
  const float bo0 = b_off[ol], bo1 = b_off[ol + 32], bo2 = b_off[ol + 64];
  __syncthreads();

  // write ow tile [row][o] (o = head*12 + point*3 + comp), pad 97
  #pragma unroll
  for (int j = 0; j < 8; ++j) {
    int r = sub * 8 + j;
    lds[r * 97 + ol]      = acc0[j] + bo0;
    lds[r * 97 + ol + 32] = acc1[j] + bo1;
    lds[r * 97 + ol + 64] = acc2[j] + bo2;
  }
  __syncthreads();

  // epilogue: 64 rows x 8 heads = 512 tasks, 2 per thread
  #pragma unroll
  for (int k = 0; k < 2; ++k) {
    int task = t + k * 256;
    int row = task & 63, head = task >> 6;
    const float* o = lds + row * 97 + head * 12;
    float ox[NP_], oy[NP_], lg[NP_];
    #pragma unroll
    for (int p = 0; p < NP_; ++p) {
      ox[p] = o[p * 3 + 0];
      oy[p] = o[p * 3 + 1];
      lg[p] = o[p * 3 + 2];
    }
    float m = fmaxf(fmaxf(lg[0], lg[1]), fmaxf(lg[2], lg[3]));
    float e[NP_];
    float s = 0.f;
    #pragma unroll
    for (int p = 0; p < NP_; ++p) { e[p] = expf(lg[p] - m); s += e[p]; }
    float inv = 1.f / s;

    int hw = hw0 + row;
    float wq = (float)(hw & 63);
    float hq = (float)(hw >> 6);
    // pixel coords: x = w + off_x * (0.1 * 0.5 * (W-1)),  0.1*0.5*63 = 3.15
    float4* dst = params + ((size_t)(b * NH_ + head) * HW_ + hw) * NP_;
    #pragma unroll
    for (int p = 0; p < NP_; ++p) {
      dst[p] = make_float4(wq + ox[p] * 3.15f, hq + oy[p] * 3.15f, e[p] * inv, 0.f);
    }
  }
}

// ---------------------------------------------------------------------------
// Kernel 2: transpose key (G, DH, HW) -> key_t (G, HW, DH)
// ---------------------------------------------------------------------------
__global__ __launch_bounds__(256) void k_transpose(const float* __restrict__ key,
                                                   float* __restrict__ key_t) {
  __shared__ float tile[32 * 65];
  const int bid = blockIdx.x;
  const int g = bid >> 6;            // 64 tiles of 64 hw each per g
  const int hw0 = (bid & 63) << 6;
  const int t = threadIdx.x;
  const float* kg = key + (size_t)g * DH_ * HW_ + hw0;
  #pragma unroll
  for (int k = 0; k < 8; ++k) {
    int idx = t + k * 256;
    int d = idx >> 6, j = idx & 63;
    tile[d * 65 + j] = kg[d * HW_ + j];
  }
  __syncthreads();
  float* kt = key_t + ((size_t)g * HW_ + hw0) * DH_;
  #pragma unroll
  for (int k = 0; k < 8; ++k) {
    int idx = t + k * 256;
    int j = idx >> 5, d = idx & 31;
    kt[j * DH_ + d] = tile[d * 65 + j];
  }
}

// ---------------------------------------------------------------------------
// Kernel 3: bilinear sample + weighted sum over points.
// One block per (b,hw); thread = channel c (head = c>>5, d = c&31).
// ---------------------------------------------------------------------------
__global__ __launch_bounds__(256) void k_sample(const float4* __restrict__ params,
                                                const float* __restrict__ key_t,
                                                float* __restrict__ feat) {
  const int bid = blockIdx.x;        // b*HW + hw
  const int b = bid >> 12;
  const int hw = bid & 4095;
  const int c = threadIdx.x;
  const int head = c >> 5, d = c & 31;
  const int g = b * NH_ + head;
  const float4* pp = params + ((size_t)g * HW_ + hw) * NP_;
  const float* kg = key_t + (size_t)g * HW_ * DH_ + d;

  float acc = 0.f;
  #pragma unroll
  for (int p = 0; p < NP_; ++p) {
    float4 pr = pp[p];
    float x = pr.x, y = pr.y, wt = pr.z;
    float x0f = floorf(x), y0f = floorf(y);
    int ix0 = (int)x0f, iy0 = (int)y0f;
    int ix1 = ix0 + 1, iy1 = iy0 + 1;
    float fx = x - x0f, fy = y - y0f;
    float gx0 = 1.f - fx, gy0 = 1.f - fy;

    bool vx0 = (ix0 >= 0) & (ix0 <= W_ - 1);
    bool vx1 = (ix1 >= 0) & (ix1 <= W_ - 1);
    bool vy0 = (iy0 >= 0) & (iy0 <= H_ - 1);
    bool vy1 = (iy1 >= 0) & (iy1 <= H_ - 1);
    int cx0 = min(max(ix0, 0), W_ - 1), cx1 = min(max(ix1, 0), W_ - 1);
    int cy0 = min(max(iy0, 0), H_ - 1), cy1 = min(max(iy1, 0), H_ - 1);

    float v00 = kg[(cy0 * W_ + cx0) * DH_];
    float v01 = kg[(cy0 * W_ + cx1) * DH_];
    float v10 = kg[(cy1 * W_ + cx0) * DH_];
    float v11 = kg[(cy1 * W_ + cx1) * DH_];

    float w00 = gx0 * gy0 * ((vx0 & vy0) ? 1.f : 0.f);
    float w01 = fx  * gy0 * ((vx1 & vy0) ? 1.f : 0.f);
    float w10 = gx0 * fy  * ((vx0 & vy1) ? 1.f : 0.f);
    float w11 = fx  * fy  * ((vx1 & vy1) ? 1.f : 0.f);

    acc = fmaf(wt, v00 * w00 + v01 * w01 + v10 * w10 + v11 * w11, acc);
  }
  feat[((size_t)b * HW_ + hw) * C_ + c] = acc;
}

// ---------------------------------------------------------------------------
// Kernel 4: out = feat @ w_proj^T + b_proj.  M=32768, N=256, K=256, f32.
// 64x64 tile, BK=32, thread 4x4 micro-tile, k-major LDS for ds_read_b128.
// ---------------------------------------------------------------------------
__global__ __launch_bounds__(256) void k_proj(const float* __restrict__ feat,
                                              const float* __restrict__ w_proj,
                                              const float* __restrict__ b_proj,
                                              float* __restrict__ out) {
  __shared__ float As[32][68];
  __shared__ float Bs[32][68];
  const int bid = blockIdx.x;
  const int nb = bid & 3;
  const int mb = bid >> 2;
  const int r0 = mb * 64, n0 = nb * 64;
  const int t = threadIdx.x;
  const int tx = t & 15, ty = t >> 4;

  float acc[4][4];
  #pragma unroll
  for (int i = 0; i < 4; ++i)
    #pragma unroll
    for (int j = 0; j < 4; ++j) acc[i][j] = 0.f;

  for (int k0 = 0; k0 < 256; k0 += 32) {
    const float* arow = feat + (size_t)r0 * 256 + k0;
    const float* brow = w_proj + (size_t)n0 * 256 + k0;
    #pragma unroll
    for (int s = 0; s < 2; ++s) {
      int idx = t + s * 256;       // float4 slot
      int row = idx >> 3;          // 0..63
      int k4 = (idx & 7) * 4;      // 0,4,...,28
      float4 a = *(const float4*)&arow[row * 256 + k4];
      float4 w = *(const float4*)&brow[row * 256 + k4];
      As[k4 + 0][row] = a.x; As[k4 + 1][row] = a.y;
      As[k4 + 2][row] = a.z; As[k4 + 3][row] = a.w;
      Bs[k4 + 0][row] = w.x; Bs[k4 + 1][row] = w.y;
      Bs[k4 + 2][row] = w.z; Bs[k4 + 3][row] = w.w;
    }
    __syncthreads();
    #pragma unroll
    for (int k = 0; k < 32; ++k) {
      float4 av = *(const float4*)&As[k][ty * 4];
      float4 bv = *(const float4*)&Bs[k][tx * 4];
      const float* ap = &av.x;
      const float* bp = &bv.x;
      #pragma unroll
      for (int i = 0; i < 4; ++i)
        #pragma unroll
        for (int j = 0; j < 4; ++j)
          acc[i][j] = fmaf(ap[i], bp[j], acc[i][j]);
    }
    __syncthreads();
  }

  const float4 bp = *(const float4*)&b_proj[n0 + tx * 4];
  const float* bpp = &bp.x;
  #pragma unroll
  for (int i = 0; i < 4; ++i) {
    float4 o;
    o.x = acc[i][0] + bpp[0];
    o.y = acc[i][1] + bpp[1];
    o.z = acc[i][2] + bpp[2];
    o.w = acc[i][3] + bpp[3];
    *(float4*)&out[((size_t)(r0 + ty * 4 + i)) * 256 + n0 + tx * 4] = o;
  }
}

// ---------------------------------------------------------------------------
extern "C" void kernel_launch(void* const* d_in, const int* in_sizes, int n_in,
                              void* d_out, int out_size, void* d_ws, size_t ws_size,
                              hipStream_t stream) {
  const float* query  = (const float*)d_in[0];
  const float* key    = (const float*)d_in[1];
  const float* w_off  = (const float*)d_in[2];
  const float* b_off  = (const float*)d_in[3];
  const float* w_proj = (const float*)d_in[4];
  const float* b_proj = (const float*)d_in[5];
  float* out = (float*)d_out;

  char* ws = (char*)d_ws;
  float4* params = (float4*)ws;                              // 16 MB
  float*  key_t  = (float*)(ws + (size_t)16 * 1024 * 1024);  // 32 MB
  float*  feat   = (float*)(ws + (size_t)48 * 1024 * 1024);  // 32 MB

  hipLaunchKernelGGL(k_offsets,  dim3(512),   dim3(256), 0, stream, query, w_off, b_off, params);
  hipLaunchKernelGGL(k_transpose,dim3(4096),  dim3(256), 0, stream, key, key_t);
  hipLaunchKernelGGL(k_sample,   dim3(32768), dim3(256), 0, stream, params, key_t, feat);
  hipLaunchKernelGGL(k_proj,     dim3(2048),  dim3(256), 0, stream, feat, w_proj, b_proj, out);
}

// Round 2
// 119.232 us; speedup vs baseline: 1.5013x; 1.5013x over previous
//
#include <hip/hip_runtime.h>
#include <cstdint>

#define B_   8
#define C_   256
#define H_   64
#define W_   64
#define HW_  4096
#define NH_  8
#define NP_  4
#define DH_  32

typedef unsigned int u32;
typedef unsigned short u16;
typedef __attribute__((ext_vector_type(8))) short bf16x8;
typedef __attribute__((ext_vector_type(4))) float f32x4;
typedef __attribute__((address_space(3))) u32 as3_u32;
typedef __attribute__((address_space(1))) u32 as1_u32;

__device__ __forceinline__ u16 f2bf(float f) {
  u32 u = __builtin_bit_cast(u32, f);
  return (u16)((u + 0x7FFFu + ((u >> 16) & 1u)) >> 16);
}
__device__ __forceinline__ float bflo(u32 v) { return __builtin_bit_cast(float, v << 16); }
__device__ __forceinline__ float bfhi(u32 v) { return __builtin_bit_cast(float, v & 0xFFFF0000u); }

// ---------------------------------------------------------------------------
// Kernel 1 (unchanged, f32): ow = q @ w_off^T + b_off -> softmax -> params
// ---------------------------------------------------------------------------
__global__ __launch_bounds__(256) void k_offsets(const float* __restrict__ query,
                                                 const float* __restrict__ w_off,
                                                 const float* __restrict__ b_off,
                                                 float4* __restrict__ params) {
  __shared__ float lds[64 * 257];
  const int bid = blockIdx.x;
  const int b   = bid >> 6;
  const int hw0 = (bid & 63) << 6;
  const int t   = threadIdx.x;

  const float* qb = query + (size_t)b * C_ * HW_ + hw0;
  #pragma unroll
  for (int k = 0; k < 64; ++k) {
    int idx = t + k * 256;
    int c = idx >> 6, hwl = idx & 63;
    lds[hwl * 257 + c] = qb[c * HW_ + hwl];
  }
  __syncthreads();

  const int sub = t >> 5, ol = t & 31;
  float acc0[8], acc1[8], acc2[8];
  #pragma unroll
  for (int j = 0; j < 8; ++j) { acc0[j] = 0.f; acc1[j] = 0.f; acc2[j] = 0.f; }

  const float* wp0 = w_off + ol * 256;
  const float* wp1 = wp0 + 32 * 256;
  const float* wp2 = wp0 + 64 * 256;
  const float* ql  = lds + (sub * 8) * 257;

  #pragma unroll 4
  for (int c = 0; c < 256; ++c) {
    float w0 = wp0[c], w1 = wp1[c], w2 = wp2[c];
    #pragma unroll
    for (int j = 0; j < 8; ++j) {
      float qv = ql[j * 257 + c];
      acc0[j] = fmaf(qv, w0, acc0[j]);
      acc1[j] = fmaf(qv, w1, acc1[j]);
      acc2[j] = fmaf(qv, w2, acc2[j]);
    }
  }
  const float bo0 = b_off[ol], bo1 = b_off[ol + 32], bo2 = b_off[ol + 64];
  __syncthreads();

  #pragma unroll
  for (int j = 0; j < 8; ++j) {
    int r = sub * 8 + j;
    lds[r * 97 + ol]      = acc0[j] + bo0;
    lds[r * 97 + ol + 32] = acc1[j] + bo1;
    lds[r * 97 + ol + 64] = acc2[j] + bo2;
  }
  __syncthreads();

  #pragma unroll
  for (int k = 0; k < 2; ++k) {
    int task = t + k * 256;
    int row = task & 63, head = task >> 6;
    const float* o = lds + row * 97 + head * 12;
    float ox[NP_], oy[NP_], lg[NP_];
    #pragma unroll
    for (int p = 0; p < NP_; ++p) {
      ox[p] = o[p * 3 + 0];
      oy[p] = o[p * 3 + 1];
      lg[p] = o[p * 3 + 2];
    }
    float m = fmaxf(fmaxf(lg[0], lg[1]), fmaxf(lg[2], lg[3]));
    float e[NP_];
    float s = 0.f;
    #pragma unroll
    for (int p = 0; p < NP_; ++p) { e[p] = expf(lg[p] - m); s += e[p]; }
    float inv = 1.f / s;

    int hw = hw0 + row;
    float wq = (float)(hw & 63);
    float hq = (float)(hw >> 6);
    float4* dst = params + ((size_t)(b * NH_ + head) * HW_ + hw) * NP_;
    #pragma unroll
    for (int p = 0; p < NP_; ++p) {
      dst[p] = make_float4(wq + ox[p] * 3.15f, hq + oy[p] * 3.15f, e[p] * inv, 0.f);
    }
  }
}

// ---------------------------------------------------------------------------
// Kernel 2: transpose key (G, DH, HW) -> key_t2 (G, HW, DH) as packed bf16 pairs
// ---------------------------------------------------------------------------
__global__ __launch_bounds__(256) void k_transpose(const float* __restrict__ key,
                                                   u32* __restrict__ key_t2) {
  __shared__ float tile[32 * 65];
  const int bid = blockIdx.x;
  const int g = bid >> 6;
  const int hw0 = (bid & 63) << 6;
  const int t = threadIdx.x;
  const float* kg = key + (size_t)g * DH_ * HW_ + hw0;
  #pragma unroll
  for (int k = 0; k < 8; ++k) {
    int idx = t + k * 256;
    int d = idx >> 6, j = idx & 63;
    tile[d * 65 + j] = kg[d * HW_ + j];
  }
  __syncthreads();
  u32* kt = key_t2 + ((size_t)g * HW_ + hw0) * 16;  // 16 u32 per row (32 bf16)
  #pragma unroll
  for (int k = 0; k < 4; ++k) {
    int idx = t + k * 256;
    int j = idx >> 4, dp = idx & 15;
    u32 v = (u32)f2bf(tile[(2 * dp) * 65 + j]) | ((u32)f2bf(tile[(2 * dp + 1) * 65 + j]) << 16);
    kt[j * 16 + dp] = v;
  }
}

// ---------------------------------------------------------------------------
// Kernel 3: convert w_proj to bf16 pairs
// ---------------------------------------------------------------------------
__global__ __launch_bounds__(256) void k_convert_w(const float* __restrict__ w,
                                                   uint2* __restrict__ wbf, int n4) {
  int i = blockIdx.x * 256 + threadIdx.x;
  if (i < n4) {
    float4 v = ((const float4*)w)[i];
    uint2 o;
    o.x = (u32)f2bf(v.x) | ((u32)f2bf(v.y) << 16);
    o.y = (u32)f2bf(v.z) | ((u32)f2bf(v.w) << 16);
    wbf[i] = o;
  }
}

// ---------------------------------------------------------------------------
// Kernel 4: bilinear sample + weighted sum. 2 channels/thread, bf16 in/out.
// Block = 256 threads = 2 hw positions x 128 channel-pairs.
// ---------------------------------------------------------------------------
__global__ __launch_bounds__(256) void k_sample(const float4* __restrict__ params,
                                                const u32* __restrict__ key_t2,
                                                u32* __restrict__ feat2) {
  const int t = threadIdx.x;
  const int hwid = blockIdx.x * 2 + (t >> 7);
  const int b = hwid >> 12;
  const int hw = hwid & 4095;
  const int c2 = t & 127;
  const int head = c2 >> 4, dp = c2 & 15;
  const int g = b * NH_ + head;
  const float4* pp = params + ((size_t)g * HW_ + hw) * NP_;
  const u32* kg = key_t2 + (size_t)g * HW_ * 16 + dp;

  float a0 = 0.f, a1 = 0.f;
  #pragma unroll
  for (int p = 0; p < NP_; ++p) {
    float4 pr = pp[p];
    float x = pr.x, y = pr.y, wt = pr.z;
    float x0f = floorf(x), y0f = floorf(y);
    int ix0 = (int)x0f, iy0 = (int)y0f;
    int ix1 = ix0 + 1, iy1 = iy0 + 1;
    float fx = x - x0f, fy = y - y0f;
    float gx0 = 1.f - fx, gy0 = 1.f - fy;

    bool vx0 = (ix0 >= 0) & (ix0 <= W_ - 1);
    bool vx1 = (ix1 >= 0) & (ix1 <= W_ - 1);
    bool vy0 = (iy0 >= 0) & (iy0 <= H_ - 1);
    bool vy1 = (iy1 >= 0) & (iy1 <= H_ - 1);
    int cx0 = min(max(ix0, 0), W_ - 1), cx1 = min(max(ix1, 0), W_ - 1);
    int cy0 = min(max(iy0, 0), H_ - 1), cy1 = min(max(iy1, 0), H_ - 1);

    u32 v00 = kg[(cy0 * W_ + cx0) * 16];
    u32 v01 = kg[(cy0 * W_ + cx1) * 16];
    u32 v10 = kg[(cy1 * W_ + cx0) * 16];
    u32 v11 = kg[(cy1 * W_ + cx1) * 16];

    float w00 = gx0 * gy0 * ((vx0 & vy0) ? 1.f : 0.f);
    float w01 = fx  * gy0 * ((vx1 & vy0) ? 1.f : 0.f);
    float w10 = gx0 * fy  * ((vx0 & vy1) ? 1.f : 0.f);
    float w11 = fx  * fy  * ((vx1 & vy1) ? 1.f : 0.f);

    a0 = fmaf(wt, w00 * bflo(v00) + w01 * bflo(v01) + w10 * bflo(v10) + w11 * bflo(v11), a0);
    a1 = fmaf(wt, w00 * bfhi(v00) + w01 * bfhi(v01) + w10 * bfhi(v10) + w11 * bfhi(v11), a1);
  }
  feat2[((size_t)b * HW_ + hw) * 128 + c2] = (u32)f2bf(a0) | ((u32)f2bf(a1) << 16);
}

// ---------------------------------------------------------------------------
// Kernel 5: out = feat @ w_proj^T + b_proj via bf16 MFMA.
// M=32768, N=256, K=256. Block tile 128x128, 4 waves (2x2), BK=32.
// LDS layout: [kq][row] of 16B slots -> conflict-free ds_read_b128 fragments.
// Staged via global_load_lds width=16 (linear dest matches [kq][row] order).
// ---------------------------------------------------------------------------
__global__ __launch_bounds__(256) void k_proj_mfma(const u16* __restrict__ A,
                                                   const u16* __restrict__ Bw,
                                                   const float* __restrict__ bias,
                                                   float* __restrict__ out) {
  __shared__ char smem[16384];  // A: [0,8K), B: [8K,16K)
  const int t = threadIdx.x, w = t >> 6, l = t & 63;
  const int wm = w >> 1, wn = w & 1;
  const int bid = blockIdx.x;
  const int nb = bid & 1, mb = bid >> 1;
  const int r0 = mb * 128, n0 = nb * 128;

  f32x4 acc[4][4];
  #pragma unroll
  for (int m = 0; m < 4; ++m)
    #pragma unroll
    for (int n = 0; n < 4; ++n)
      acc[m][n] = (f32x4){0.f, 0.f, 0.f, 0.f};

  for (int k0 = 0; k0 < 256; k0 += 32) {
    // stage: 16 x 1KB issues (8 A + 8 B), 4 per wave
    if (w < 2) {
      #pragma unroll
      for (int j = 0; j < 4; ++j) {
        int i = w * 4 + j;              // 0..7
        int kq = i >> 1, half = i & 1;
        const u16* g = A + ((size_t)(r0 + half * 64 + l)) * 256 + k0 + kq * 8;
        __builtin_amdgcn_global_load_lds((const as1_u32*)g, (as3_u32*)(smem + i * 1024), 16, 0, 0);
      }
    } else {
      #pragma unroll
      for (int j = 0; j < 4; ++j) {
        int i = (w - 2) * 4 + j;        // 0..7
        int kq = i >> 1, half = i & 1;
        const u16* g = Bw + ((size_t)(n0 + half * 64 + l)) * 256 + k0 + kq * 8;
        __builtin_amdgcn_global_load_lds((const as1_u32*)g, (as3_u32*)(smem + 8192 + i * 1024), 16, 0, 0);
      }
    }
    __syncthreads();

    const int kq = l >> 4, lr = l & 15;
    bf16x8 af[4], bfr[4];
    #pragma unroll
    for (int m = 0; m < 4; ++m)
      af[m] = *(const bf16x8*)(smem + (kq * 128 + wm * 64 + m * 16 + lr) * 16);
    #pragma unroll
    for (int n = 0; n < 4; ++n)
      bfr[n] = *(const bf16x8*)(smem + 8192 + (kq * 128 + wn * 64 + n * 16 + lr) * 16);
    #pragma unroll
    for (int m = 0; m < 4; ++m)
      #pragma unroll
      for (int n = 0; n < 4; ++n)
        acc[m][n] = __builtin_amdgcn_mfma_f32_16x16x32_bf16(af[m], bfr[n], acc[m][n], 0, 0, 0);
    __syncthreads();
  }

  const int lr = l & 15, lq = l >> 4;
  #pragma unroll
  for (int n = 0; n < 4; ++n) {
    int col = n0 + wn * 64 + n * 16 + lr;
    float bv = bias[col];
    #pragma unroll
    for (int m = 0; m < 4; ++m) {
      int row = r0 + wm * 64 + m * 16 + lq * 4;
      #pragma unroll
      for (int r = 0; r < 4; ++r)
        out[(size_t)(row + r) * 256 + col] = acc[m][n][r] + bv;
    }
  }
}

// ---------------------------------------------------------------------------
extern "C" void kernel_launch(void* const* d_in, const int* in_sizes, int n_in,
                              void* d_out, int out_size, void* d_ws, size_t ws_size,
                              hipStream_t stream) {
  const float* query  = (const float*)d_in[0];
  const float* key    = (const float*)d_in[1];
  const float* w_off  = (const float*)d_in[2];
  const float* b_off  = (const float*)d_in[3];
  const float* w_proj = (const float*)d_in[4];
  const float* b_proj = (const float*)d_in[5];
  float* out = (float*)d_out;

  char* ws = (char*)d_ws;
  float4* params   = (float4*)ws;                               // 16 MB
  u32*    key_t2   = (u32*)(ws + (size_t)16 * 1024 * 1024);     // 16 MB
  u32*    feat2    = (u32*)(ws + (size_t)32 * 1024 * 1024);     // 16 MB
  uint2*  wproj_bf = (uint2*)(ws + (size_t)48 * 1024 * 1024);   // 128 KB

  hipLaunchKernelGGL(k_offsets,   dim3(512),   dim3(256), 0, stream, query, w_off, b_off, params);
  hipLaunchKernelGGL(k_transpose, dim3(4096),  dim3(256), 0, stream, key, key_t2);
  hipLaunchKernelGGL(k_convert_w, dim3(64),    dim3(256), 0, stream, w_proj, wproj_bf, 16384);
  hipLaunchKernelGGL(k_sample,    dim3(16384), dim3(256), 0, stream, params, key_t2, feat2);
  hipLaunchKernelGGL(k_proj_mfma, dim3(512),   dim3(256), 0, stream,
                     (const u16*)feat2, (const u16*)wproj_bf, b_proj, out);
}

// Round 3
// 83.110 us; speedup vs baseline: 2.1538x; 1.4346x over previous
//
#include <hip/hip_runtime.h>
#include <cstdint>

#define B_   8
#define C_   256
#define H_   64
#define W_   64
#define HW_  4096
#define NH_  8
#define NP_  4
#define DH_  32

typedef unsigned int u32;
typedef unsigned short u16;
typedef __attribute__((ext_vector_type(8))) short bf16x8;
typedef __attribute__((ext_vector_type(4))) float f32x4;
typedef __attribute__((ext_vector_type(4))) u32 u32x4;
typedef __attribute__((address_space(3))) u32 as3_u32;
typedef __attribute__((address_space(1))) u32 as1_u32;

__device__ __forceinline__ u16 f2bf(float f) {
  u32 u = __builtin_bit_cast(u32, f);
  return (u16)((u + 0x7FFFu + ((u >> 16) & 1u)) >> 16);
}
__device__ __forceinline__ float bflo(u32 v) { return __builtin_bit_cast(float, v << 16); }
__device__ __forceinline__ float bfhi(u32 v) { return __builtin_bit_cast(float, v & 0xFFFF0000u); }

// ---------------------------------------------------------------------------
// Kernel 1: offsets GEMM via bf16 MFMA, q-transpose fused into LDS staging.
// D[row=b*hw][o] = sum_c q[b][c][hw] * w_off[o][c]; softmax epilogue -> params.
// M=32768, N=96, K=256. Block: 128 rows, 4 waves (each 32 rows x 96 cols).
// A LDS: [kq 0..3][row 0..127] 16B slots (8 consecutive k per slot).
// B LDS: [col][chunk ^ (col&7)] 16B slots (XOR swizzle kills 512B-stride conflict).
// ---------------------------------------------------------------------------
__global__ __launch_bounds__(256) void k_offsets_mfma(const float* __restrict__ query,
                                                      const float* __restrict__ w_off,
                                                      const float* __restrict__ b_off,
                                                      float4* __restrict__ params) {
  __shared__ char smem[57344];  // B: [0,48K) ; A: [48K,56K) ; epilogue aliases [0,50.2K)
  const int t = threadIdx.x, l = t & 63, w = t >> 6;
  const int lr = l & 15, lq = l >> 4;
  const int r0 = blockIdx.x * 128;
  const int b  = r0 >> 12;
  const int hw0 = r0 & 4095;

  // one-time B stage: w_off (96x256 f32, row-major) -> bf16 LDS with chunk XOR swizzle
  {
    const float4* w4 = (const float4*)w_off;
    #pragma unroll
    for (int j = 0; j < 12; ++j) {
      int m = t + j * 256;               // memory chunk index: col*32 + chunk
      int col = m >> 5, ch = m & 31;
      float4 lo = w4[m * 2];
      float4 hi = w4[m * 2 + 1];
      u32x4 v;
      v.x = (u32)f2bf(lo.x) | ((u32)f2bf(lo.y) << 16);
      v.y = (u32)f2bf(lo.z) | ((u32)f2bf(lo.w) << 16);
      v.z = (u32)f2bf(hi.x) | ((u32)f2bf(hi.y) << 16);
      v.w = (u32)f2bf(hi.z) | ((u32)f2bf(hi.w) << 16);
      int slot = (col << 5) | (ch ^ (col & 7));
      *(u32x4*)(smem + slot * 16) = v;
    }
  }

  f32x4 acc[2][6];
  #pragma unroll
  for (int m = 0; m < 2; ++m)
    #pragma unroll
    for (int n = 0; n < 6; ++n)
      acc[m][n] = (f32x4){0.f, 0.f, 0.f, 0.f};

  for (int step = 0; step < 8; ++step) {
    const int k0 = step * 32;
    // A stage: transpose-convert 32c x 128hw from query into [kq][row] slots
    #pragma unroll
    for (int it = 0; it < 8; ++it) {
      int idx = t + it * 256;            // 0..2047
      int i = idx & 127;                 // row (hw)
      int p = idx >> 7;                  // k-pair 0..15
      const float* src = query + ((size_t)(b * 256 + k0 + 2 * p)) * 4096 + hw0 + i;
      u32 v = (u32)f2bf(src[0]) | ((u32)f2bf(src[4096]) << 16);
      *(u32*)(smem + 49152 + ((p >> 2) * 128 + i) * 16 + (p & 3) * 4) = v;
    }
    __syncthreads();

    const int chb = step * 4 + lq;
    bf16x8 bfr[6], af[2];
    #pragma unroll
    for (int n = 0; n < 6; ++n) {
      int col = n * 16 + lr;
      bfr[n] = *(const bf16x8*)(smem + ((col << 5) | (chb ^ (col & 7))) * 16);
    }
    #pragma unroll
    for (int m = 0; m < 2; ++m)
      af[m] = *(const bf16x8*)(smem + 49152 + (lq * 128 + w * 32 + m * 16 + lr) * 16);

    #pragma unroll
    for (int m = 0; m < 2; ++m)
      #pragma unroll
      for (int n = 0; n < 6; ++n)
        acc[m][n] = __builtin_amdgcn_mfma_f32_16x16x32_bf16(af[m], bfr[n], acc[m][n], 0, 0, 0);
    __syncthreads();
  }

  // epilogue: acc -> LDS [row][o] (stride 98 words), + bias
  float* epi = (float*)smem;
  #pragma unroll
  for (int n = 0; n < 6; ++n) {
    int o = n * 16 + lr;
    float bo = b_off[o];
    #pragma unroll
    for (int m = 0; m < 2; ++m) {
      int row = w * 32 + m * 16 + lq * 4;
      #pragma unroll
      for (int r = 0; r < 4; ++r)
        epi[(row + r) * 98 + o] = acc[m][n][r] + bo;
    }
  }
  __syncthreads();

  // softmax over points + position emit: 128 rows x 8 heads = 1024 tasks
  #pragma unroll
  for (int k = 0; k < 4; ++k) {
    int task = t + k * 256;
    int row = task & 127, head = task >> 7;
    const float* o = epi + row * 98 + head * 12;
    float ox[NP_], oy[NP_], lg[NP_];
    #pragma unroll
    for (int p = 0; p < NP_; ++p) {
      ox[p] = o[p * 3 + 0];
      oy[p] = o[p * 3 + 1];
      lg[p] = o[p * 3 + 2];
    }
    float mx = fmaxf(fmaxf(lg[0], lg[1]), fmaxf(lg[2], lg[3]));
    float e[NP_];
    float s = 0.f;
    #pragma unroll
    for (int p = 0; p < NP_; ++p) { e[p] = expf(lg[p] - mx); s += e[p]; }
    float inv = 1.f / s;

    int grow = r0 + row;
    int hw = grow & 4095;
    float wq = (float)(hw & 63);
    float hq = (float)(hw >> 6);
    float4* dst = params + ((size_t)(b * NH_ + head) * HW_ + hw) * NP_;
    #pragma unroll
    for (int p = 0; p < NP_; ++p) {
      dst[p] = make_float4(wq + ox[p] * 3.15f, hq + oy[p] * 3.15f, e[p] * inv, 0.f);
    }
  }
}

// ---------------------------------------------------------------------------
// Kernel 2: transpose key (G, DH, HW) -> key_t2 (G, HW, DH) as packed bf16 pairs
// ---------------------------------------------------------------------------
__global__ __launch_bounds__(256) void k_transpose(const float* __restrict__ key,
                                                   u32* __restrict__ key_t2) {
  __shared__ float tile[32 * 65];
  const int bid = blockIdx.x;
  const int g = bid >> 6;
  const int hw0 = (bid & 63) << 6;
  const int t = threadIdx.x;
  const float* kg = key + (size_t)g * DH_ * HW_ + hw0;
  #pragma unroll
  for (int k = 0; k < 8; ++k) {
    int idx = t + k * 256;
    int d = idx >> 6, j = idx & 63;
    tile[d * 65 + j] = kg[d * HW_ + j];
  }
  __syncthreads();
  u32* kt = key_t2 + ((size_t)g * HW_ + hw0) * 16;
  #pragma unroll
  for (int k = 0; k < 4; ++k) {
    int idx = t + k * 256;
    int j = idx >> 4, dp = idx & 15;
    u32 v = (u32)f2bf(tile[(2 * dp) * 65 + j]) | ((u32)f2bf(tile[(2 * dp + 1) * 65 + j]) << 16);
    kt[j * 16 + dp] = v;
  }
}

// ---------------------------------------------------------------------------
// Kernel 3: convert w_proj to bf16 pairs
// ---------------------------------------------------------------------------
__global__ __launch_bounds__(256) void k_convert_w(const float* __restrict__ w,
                                                   uint2* __restrict__ wbf, int n4) {
  int i = blockIdx.x * 256 + threadIdx.x;
  if (i < n4) {
    float4 v = ((const float4*)w)[i];
    uint2 o;
    o.x = (u32)f2bf(v.x) | ((u32)f2bf(v.y) << 16);
    o.y = (u32)f2bf(v.z) | ((u32)f2bf(v.w) << 16);
    wbf[i] = o;
  }
}

// ---------------------------------------------------------------------------
// Kernel 4: bilinear sample + weighted sum. 2 channels/thread, bf16 in/out.
// ---------------------------------------------------------------------------
__global__ __launch_bounds__(256) void k_sample(const float4* __restrict__ params,
                                                const u32* __restrict__ key_t2,
                                                u32* __restrict__ feat2) {
  const int t = threadIdx.x;
  const int hwid = blockIdx.x * 2 + (t >> 7);
  const int b = hwid >> 12;
  const int hw = hwid & 4095;
  const int c2 = t & 127;
  const int head = c2 >> 4, dp = c2 & 15;
  const int g = b * NH_ + head;
  const float4* pp = params + ((size_t)g * HW_ + hw) * NP_;
  const u32* kg = key_t2 + (size_t)g * HW_ * 16 + dp;

  float a0 = 0.f, a1 = 0.f;
  #pragma unroll
  for (int p = 0; p < NP_; ++p) {
    float4 pr = pp[p];
    float x = pr.x, y = pr.y, wt = pr.z;
    float x0f = floorf(x), y0f = floorf(y);
    int ix0 = (int)x0f, iy0 = (int)y0f;
    int ix1 = ix0 + 1, iy1 = iy0 + 1;
    float fx = x - x0f, fy = y - y0f;
    float gx0 = 1.f - fx, gy0 = 1.f - fy;

    bool vx0 = (ix0 >= 0) & (ix0 <= W_ - 1);
    bool vx1 = (ix1 >= 0) & (ix1 <= W_ - 1);
    bool vy0 = (iy0 >= 0) & (iy0 <= H_ - 1);
    bool vy1 = (iy1 >= 0) & (iy1 <= H_ - 1);
    int cx0 = min(max(ix0, 0), W_ - 1), cx1 = min(max(ix1, 0), W_ - 1);
    int cy0 = min(max(iy0, 0), H_ - 1), cy1 = min(max(iy1, 0), H_ - 1);

    u32 v00 = kg[(cy0 * W_ + cx0) * 16];
    u32 v01 = kg[(cy0 * W_ + cx1) * 16];
    u32 v10 = kg[(cy1 * W_ + cx0) * 16];
    u32 v11 = kg[(cy1 * W_ + cx1) * 16];

    float w00 = gx0 * gy0 * ((vx0 & vy0) ? 1.f : 0.f);
    float w01 = fx  * gy0 * ((vx1 & vy0) ? 1.f : 0.f);
    float w10 = gx0 * fy  * ((vx0 & vy1) ? 1.f : 0.f);
    float w11 = fx  * fy  * ((vx1 & vy1) ? 1.f : 0.f);

    a0 = fmaf(wt, w00 * bflo(v00) + w01 * bflo(v01) + w10 * bflo(v10) + w11 * bflo(v11), a0);
    a1 = fmaf(wt, w00 * bfhi(v00) + w01 * bfhi(v01) + w10 * bfhi(v10) + w11 * bfhi(v11), a1);
  }
  feat2[((size_t)b * HW_ + hw) * 128 + c2] = (u32)f2bf(a0) | ((u32)f2bf(a1) << 16);
}

// ---------------------------------------------------------------------------
// Kernel 5: out = feat @ w_proj^T + b_proj via bf16 MFMA (unchanged).
// ---------------------------------------------------------------------------
__global__ __launch_bounds__(256) void k_proj_mfma(const u16* __restrict__ A,
                                                   const u16* __restrict__ Bw,
                                                   const float* __restrict__ bias,
                                                   float* __restrict__ out) {
  __shared__ char smem[16384];
  const int t = threadIdx.x, w = t >> 6, l = t & 63;
  const int wm = w >> 1, wn = w & 1;
  const int bid = blockIdx.x;
  const int nb = bid & 1, mb = bid >> 1;
  const int r0 = mb * 128, n0 = nb * 128;

  f32x4 acc[4][4];
  #pragma unroll
  for (int m = 0; m < 4; ++m)
    #pragma unroll
    for (int n = 0; n < 4; ++n)
      acc[m][n] = (f32x4){0.f, 0.f, 0.f, 0.f};

  for (int k0 = 0; k0 < 256; k0 += 32) {
    if (w < 2) {
      #pragma unroll
      for (int j = 0; j < 4; ++j) {
        int i = w * 4 + j;
        int kq = i >> 1, half = i & 1;
        const u16* g = A + ((size_t)(r0 + half * 64 + l)) * 256 + k0 + kq * 8;
        __builtin_amdgcn_global_load_lds((const as1_u32*)g, (as3_u32*)(smem + i * 1024), 16, 0, 0);
      }
    } else {
      #pragma unroll
      for (int j = 0; j < 4; ++j) {
        int i = (w - 2) * 4 + j;
        int kq = i >> 1, half = i & 1;
        const u16* g = Bw + ((size_t)(n0 + half * 64 + l)) * 256 + k0 + kq * 8;
        __builtin_amdgcn_global_load_lds((const as1_u32*)g, (as3_u32*)(smem + 8192 + i * 1024), 16, 0, 0);
      }
    }
    __syncthreads();

    const int kq = l >> 4, lr = l & 15;
    bf16x8 af[4], bfr[4];
    #pragma unroll
    for (int m = 0; m < 4; ++m)
      af[m] = *(const bf16x8*)(smem + (kq * 128 + wm * 64 + m * 16 + lr) * 16);
    #pragma unroll
    for (int n = 0; n < 4; ++n)
      bfr[n] = *(const bf16x8*)(smem + 8192 + (kq * 128 + wn * 64 + n * 16 + lr) * 16);
    #pragma unroll
    for (int m = 0; m < 4; ++m)
      #pragma unroll
      for (int n = 0; n < 4; ++n)
        acc[m][n] = __builtin_amdgcn_mfma_f32_16x16x32_bf16(af[m], bfr[n], acc[m][n], 0, 0, 0);
    __syncthreads();
  }

  const int lr = l & 15, lq = l >> 4;
  #pragma unroll
  for (int n = 0; n < 4; ++n) {
    int col = n0 + wn * 64 + n * 16 + lr;
    float bv = bias[col];
    #pragma unroll
    for (int m = 0; m < 4; ++m) {
      int row = r0 + wm * 64 + m * 16 + lq * 4;
      #pragma unroll
      for (int r = 0; r < 4; ++r)
        out[(size_t)(row + r) * 256 + col] = acc[m][n][r] + bv;
    }
  }
}

// ---------------------------------------------------------------------------
extern "C" void kernel_launch(void* const* d_in, const int* in_sizes, int n_in,
                              void* d_out, int out_size, void* d_ws, size_t ws_size,
                              hipStream_t stream) {
  const float* query  = (const float*)d_in[0];
  const float* key    = (const float*)d_in[1];
  const float* w_off  = (const float*)d_in[2];
  const float* b_off  = (const float*)d_in[3];
  const float* w_proj = (const float*)d_in[4];
  const float* b_proj = (const float*)d_in[5];
  float* out = (float*)d_out;

  char* ws = (char*)d_ws;
  float4* params   = (float4*)ws;                               // 16 MB
  u32*    key_t2   = (u32*)(ws + (size_t)16 * 1024 * 1024);     // 16 MB
  u32*    feat2    = (u32*)(ws + (size_t)32 * 1024 * 1024);     // 16 MB
  uint2*  wproj_bf = (uint2*)(ws + (size_t)48 * 1024 * 1024);   // 128 KB

  hipLaunchKernelGGL(k_offsets_mfma, dim3(256),   dim3(256), 0, stream, query, w_off, b_off, params);
  hipLaunchKernelGGL(k_transpose,    dim3(4096),  dim3(256), 0, stream, key, key_t2);
  hipLaunchKernelGGL(k_convert_w,    dim3(64),    dim3(256), 0, stream, w_proj, wproj_bf, 16384);
  hipLaunchKernelGGL(k_sample,       dim3(16384), dim3(256), 0, stream, params, key_t2, feat2);
  hipLaunchKernelGGL(k_proj_mfma,    dim3(512),   dim3(256), 0, stream,
                     (const u16*)feat2, (const u16*)wproj_bf, b_proj, out);
}